// Round 1
// baseline (477.697 us; speedup 1.0000x reference)
//
#include <hip/hip_runtime.h>

#define A_ALLELES 4096
#define CCH 12     // input channels
#define LW 32      // read window length
#define DH 32      // hidden dim

// ---------------------------------------------------------------------------
// Kernel 1: exclusive prefix-sum of the two per-allele read-count arrays.
// A=4096 counts per source; 256 threads x 16 elems each, Hillis-Steele on
// the 256 per-thread partials. blockIdx.x selects the source.
// ---------------------------------------------------------------------------
__global__ __launch_bounds__(256) void scan_kernel(
    const int* __restrict__ c0, const int* __restrict__ c1,
    int* __restrict__ o0, int* __restrict__ o1)
{
    const int* c = (blockIdx.x == 0) ? c0 : c1;
    int*       o = (blockIdx.x == 0) ? o0 : o1;

    __shared__ int part[256];
    const int tid  = threadIdx.x;
    const int base = tid * 16;

    int loc[16];
    int s = 0;
#pragma unroll
    for (int i = 0; i < 16; ++i) { loc[i] = c[base + i]; s += loc[i]; }
    part[tid] = s;
    __syncthreads();

    for (int st = 1; st < 256; st <<= 1) {
        int v = (tid >= st) ? part[tid - st] : 0;
        __syncthreads();
        part[tid] += v;
        __syncthreads();
    }

    int excl = (tid == 0) ? 0 : part[tid - 1];
#pragma unroll
    for (int i = 0; i < 16; ++i) { o[base + i] = excl; excl += loc[i]; }
}

// ---------------------------------------------------------------------------
// Kernel 2: fused frames+relu+segment-sum+normalize+mean+head.
// One wave per (allele, source) pair: p in [0, 8192). Lane task = (read,
// 4-consecutive-l group): 12 float4 global loads, 32x48 fp32 FMA vs W in
// LDS (wave-uniform ds_read_b128 -> broadcast), relu-accumulate into
// acc[32]. Butterfly shfl reduce, fold 1/(32*depth) and the W2 head,
// atomicAdd into zeroed d_out.
// ---------------------------------------------------------------------------
__global__ __launch_bounds__(256) void main_kernel(
    const float* __restrict__ t0, const float* __restrict__ t1,
    const float* __restrict__ W0, const float* __restrict__ b0,
    const float* __restrict__ W1, const float* __restrict__ b1,
    const float* __restrict__ W2, const float* __restrict__ b2,
    const int*  __restrict__ cnt0, const int* __restrict__ cnt1,
    const float* __restrict__ dm0, const float* __restrict__ dm1,
    const int*  __restrict__ offs0, const int* __restrict__ offs1,
    float* __restrict__ out)
{
    __shared__ float sW[2][DH][CCH];     // 2*32*12 floats; 48B rows, 16B aligned
    __shared__ float sB[2][DH];
    __shared__ float sW2[2 * 2 * DH];    // [NOUT][2D] flat = 128
    __shared__ float sB2[2];

    const int tid = threadIdx.x;
    for (int i = tid; i < DH * CCH; i += 256) {
        sW[0][i / CCH][i % CCH] = W0[i];
        sW[1][i / CCH][i % CCH] = W1[i];
    }
    if (tid < DH) { sB[0][tid] = b0[tid]; sB[1][tid] = b1[tid]; }
    if (tid < 2 * 2 * DH) sW2[tid] = W2[tid];
    if (tid < 2) sB2[tid] = b2[tid];
    __syncthreads();

    const int wave = tid >> 6;
    const int lane = tid & 63;
    const int p    = blockIdx.x * 4 + wave;   // 0..8191
    const int src  = p >> 12;                 // 0: source0, 1: source1
    const int a    = p & (A_ALLELES - 1);

    const float* tens = src ? t1 : t0;
    const int*   cnt  = src ? cnt1 : cnt0;
    const int*   offs = src ? offs1 : offs0;
    const float* dm   = src ? dm1 : dm0;

    const int n     = cnt[a];
    const int start = offs[a];
    const float* base = tens + (size_t)start * (CCH * LW);

    float acc[DH];
#pragma unroll
    for (int d = 0; d < DH; ++d) acc[d] = 0.f;

    const int tasks = n * (LW / 4);           // (read, l-group-of-4) tasks
    for (int tsk = lane; tsk < tasks; tsk += 64) {
        const float* rp = base + (size_t)(tsk >> 3) * (CCH * LW) + (tsk & 7) * 4;
        float4 v[CCH];
#pragma unroll
        for (int c = 0; c < CCH; ++c)
            v[c] = *(const float4*)(rp + c * LW);

#pragma unroll
        for (int d = 0; d < DH; ++d) {
            const float4* wrow = (const float4*)(&sW[src][d][0]);
            float4 wA = wrow[0], wB = wrow[1], wC = wrow[2];  // ds_read_b128 x3
            float wv[CCH] = { wA.x, wA.y, wA.z, wA.w,
                              wB.x, wB.y, wB.z, wB.w,
                              wC.x, wC.y, wC.z, wC.w };
            const float bb = sB[src][d];
            float x0 = bb, x1 = bb, x2 = bb, x3 = bb;
#pragma unroll
            for (int c = 0; c < CCH; ++c) {
                x0 = fmaf(v[c].x, wv[c], x0);
                x1 = fmaf(v[c].y, wv[c], x1);
                x2 = fmaf(v[c].z, wv[c], x2);
                x3 = fmaf(v[c].w, wv[c], x3);
            }
            acc[d] += (fmaxf(x0, 0.f) + fmaxf(x1, 0.f)) +
                      (fmaxf(x2, 0.f) + fmaxf(x3, 0.f));
        }
    }

    // wave butterfly reduction: every lane ends with the full per-allele sums
#pragma unroll
    for (int d = 0; d < DH; ++d) {
#pragma unroll
        for (int m = 32; m >= 1; m >>= 1)
            acc[d] += __shfl_xor(acc[d], m, 64);
    }

    const float scale = 1.f / (32.f * dm[a]);
    if (lane == 0) {
        float p0 = 0.f, p1 = 0.f;
#pragma unroll
        for (int d = 0; d < DH; ++d) {
            const float pv = acc[d] * scale;
            p0 = fmaf(pv, sW2[0 * 2 * DH + src * DH + d], p0);
            p1 = fmaf(pv, sW2[1 * 2 * DH + src * DH + d], p1);
        }
        if (src == 0) { p0 += sB2[0]; p1 += sB2[1]; }
        atomicAdd(&out[a * 2 + 0], p0);
        atomicAdd(&out[a * 2 + 1], p1);
    }
}

extern "C" void kernel_launch(void* const* d_in, const int* in_sizes, int n_in,
                              void* d_out, int out_size, void* d_ws, size_t ws_size,
                              hipStream_t stream) {
    const float* t0  = (const float*)d_in[0];
    const float* t1  = (const float*)d_in[1];
    const float* W0  = (const float*)d_in[2];
    const float* b0  = (const float*)d_in[3];
    const float* W1  = (const float*)d_in[4];
    const float* b1  = (const float*)d_in[5];
    const float* W2  = (const float*)d_in[6];
    const float* b2  = (const float*)d_in[7];
    const int*  cnt0 = (const int*)d_in[8];
    const int*  cnt1 = (const int*)d_in[9];
    // d_in[10] = numAllelesPerSite (unused by the reference math)
    const float* dm0 = (const float*)d_in[11];
    const float* dm1 = (const float*)d_in[12];

    int* offs0 = (int*)d_ws;
    int* offs1 = offs0 + A_ALLELES;

    hipMemsetAsync(d_out, 0, (size_t)out_size * sizeof(float), stream);
    scan_kernel<<<2, 256, 0, stream>>>(cnt0, cnt1, offs0, offs1);

    main_kernel<<<2048, 256, 0, stream>>>(
        t0, t1, W0, b0, W1, b1, W2, b2,
        cnt0, cnt1, dm0, dm1, offs0, offs1, (float*)d_out);
}